// Round 2
// baseline (6198.569 us; speedup 1.0000x reference)
//
#include <hip/hip_runtime.h>
#include <math.h>

#define NPTS    32768
#define NPOINT  2048
#define NSAMPLE 32
#define RADIUS2 0.25f
#define D_IN    64
#define D0      67
#define H1DIM   64
#define H2DIM   128

// ---------------------------------------------------------------------------
// Kernel A: SINGLE-BLOCK FPS + heaters.
// R11: single 1024-thread block does the full 32K-point distance update +
// argmax on ONE CU -- no fabric on the critical path (the 32-block version
// was stuck at 2.17us/iter of cross-XCD publish->observe latency).
// R12 fix: R11 came back at 3.12us/iter with VGPR_Count=64 -- the compiler
// allocated for 8-waves/EU occupancy and spilled the 74-float persistent
// state (X/Y/Z[14]+D[32]) to scratch. __launch_bounds__(1024, 4) declares
// the true occupancy (16 waves = 1 block/CU = 4 waves/EU) raising the VGPR
// cap to 128; peak live ~112 fits, spills vanish.
// Point storage per thread (32 pts): 14 in VGPRs, 5 in LDS-as-private
// (planar float2+float, conflict-free, ~60KB -> 1 block/CU),
// 13 streamed from L2 each iter (xyz 384KB is L2-resident on this XCD).
// Argmax: wave butterfly -> 16-entry LDS -> redundant cross-wave butterfly
// (no broadcast barrier) -> equality rescan + LDS atomicMin (exact
// first-occurrence tie-break == jnp.argmax). widx ping-pong parity slots
// remove the 3rd barrier.
// Exact numerics: same op order as before -- sub,mul,mul,add,mul,add,
// fminf -- under fp contract(off).
// Heaters: blocks 1..255, 256 active threads each keep clocks up for the
// tail kernels (measured: tail 350us -> 30us with heat).
// ---------------------------------------------------------------------------
#define FT    1024
#define RPTS  14                 // register-resident points / thread
#define LPTS  5                  // LDS-resident points / thread (~60KB block)
#define GPTS  13                 // L2-streamed points / thread
#define TPTS  (RPTS + LPTS + GPTS)   // 32; TPTS*FT == NPTS
#define HEAT_DONE 0x600DD00Du
#define HEAT_CAP  4096           // outer-loop safety cap (~55ms)

__global__ __launch_bounds__(1024, 4) void fps_heat_kernel(const float* __restrict__ xyz,
                                                           float* __restrict__ d_out,
                                                           unsigned int* __restrict__ flag,
                                                           float* __restrict__ hdump)
{
#pragma clang fp contract(off)
    const int t = threadIdx.x;
    const int b = blockIdx.x;

    if (b != 0) {
        // ----------------- HEATER: dense FMA, poll flag every ~13us --------
        if (t >= 256) return;    // 4 waves/heater block
        float a0 = 1.0f + (float)(b * 256 + t) * 1e-6f;
        float a1 = a0 + 0.1f, a2 = a0 + 0.2f, a3 = a0 + 0.3f;
        float a4 = a0 + 0.4f, a5 = a0 + 0.5f, a6 = a0 + 0.6f, a7 = a0 + 0.7f;
        for (int outer = 0; outer < HEAT_CAP; ++outer) {
            #pragma unroll 8
            for (int n = 0; n < 2048; ++n) {
                a0 = fmaf(a0, 0.9999999f, 1e-7f);
                a1 = fmaf(a1, 0.9999999f, 1e-7f);
                a2 = fmaf(a2, 0.9999999f, 1e-7f);
                a3 = fmaf(a3, 0.9999999f, 1e-7f);
                a4 = fmaf(a4, 0.9999999f, 1e-7f);
                a5 = fmaf(a5, 0.9999999f, 1e-7f);
                a6 = fmaf(a6, 0.9999999f, 1e-7f);
                a7 = fmaf(a7, 0.9999999f, 1e-7f);
            }
            if (__hip_atomic_load(flag, __ATOMIC_RELAXED,
                                  __HIP_MEMORY_SCOPE_AGENT) == HEAT_DONE)
                break;
        }
        float s = a0 + a1 + a2 + a3 + a4 + a5 + a6 + a7;
        if (s == 1234.56789f) hdump[(b - 1) * 256 + t] = s;   // never true
        return;
    }

    // ------------------------------ FPS block ------------------------------
    __shared__ float2 LXY[LPTS * FT];   // 40 KB  (x,y planar pairs)
    __shared__ float  LZ [LPTS * FT];   // 20 KB
    __shared__ float  red[16];
    __shared__ int    widx2[2];

    float X[RPTS], Y[RPTS], Z[RPTS];
    float D[TPTS];
    #pragma unroll
    for (int k = 0; k < TPTS; ++k) D[k] = 1e38f;

    // one-time staging: slots 0..13 -> regs, 14..18 -> private LDS
    #pragma unroll
    for (int k = 0; k < RPTS; ++k) {
        const int p = k * FT + t;
        X[k] = xyz[3 * p + 0];
        Y[k] = xyz[3 * p + 1];
        Z[k] = xyz[3 * p + 2];
    }
    #pragma unroll
    for (int j = 0; j < LPTS; ++j) {
        const int p = (RPTS + j) * FT + t;
        LXY[j * FT + t] = make_float2(xyz[3 * p + 0], xyz[3 * p + 1]);
        LZ [j * FT + t] = xyz[3 * p + 2];
    }
    if (t == 0) { widx2[0] = 0x7fffffff; widx2[1] = 0x7fffffff; }
    float fx = xyz[0], fy = xyz[1], fz = xyz[2];   // far = 0 at start
    __syncthreads();

// one point: exact op order (sub, mul, mul, add, mul, add, fmin)
#define PSTEP(px, py, pz, slot) ({                          \
        float dx_ = (px) - fx, dy_ = (py) - fy, dz_ = (pz) - fz; \
        float d_  = ((dx_ * dx_) + (dy_ * dy_)) + (dz_ * dz_);   \
        float Dn_ = fminf(D[slot], d_);                          \
        D[slot] = Dn_;                                           \
        Dn_; })

    for (int i = 0; i < NPOINT; ++i) {
        const int par = i & 1;

        if (t == 0) {   // emit current far point's coords
            d_out[3 * i + 0] = fx;
            d_out[3 * i + 1] = fy;
            d_out[3 * i + 2] = fz;
        }

        float m0 = -1.0f, m1 = -1.0f, m2 = -1.0f, m3 = -1.0f;

        // --- L2-streamed batch A loads issued early (slots 19..25) ---------
        float gx[7], gy[7], gz[7];
        #pragma unroll
        for (int j = 0; j < 7; ++j) {
            const int p = (RPTS + LPTS + j) * FT + t;
            gx[j] = xyz[3 * p + 0];
            gy[j] = xyz[3 * p + 1];
            gz[j] = xyz[3 * p + 2];
        }

        // --- register slice (slots 0..13), pairs -> max3 fusion ------------
        #pragma unroll
        for (int k = 0; k < RPTS; k += 2) {
            float a = PSTEP(X[k + 0], Y[k + 0], Z[k + 0], k + 0);
            float c = PSTEP(X[k + 1], Y[k + 1], Z[k + 1], k + 1);
            m0 = fmaxf(fmaxf(m0, a), c);
        }

        // --- LDS slice (slots 14..18) --------------------------------------
        #pragma unroll
        for (int j = 0; j < 4; j += 2) {
            float2 q0 = LXY[(j + 0) * FT + t]; float z0 = LZ[(j + 0) * FT + t];
            float2 q1 = LXY[(j + 1) * FT + t]; float z1 = LZ[(j + 1) * FT + t];
            float a = PSTEP(q0.x, q0.y, z0, RPTS + j + 0);
            float c = PSTEP(q1.x, q1.y, z1, RPTS + j + 1);
            m1 = fmaxf(fmaxf(m1, a), c);
        }
        {
            float2 q4 = LXY[4 * FT + t]; float z4 = LZ[4 * FT + t];
            m1 = fmaxf(m1, PSTEP(q4.x, q4.y, z4, RPTS + 4));
        }

        // --- streamed batch A compute (slots 19..25) -----------------------
        #pragma unroll
        for (int j = 0; j < 6; j += 2) {
            float a = PSTEP(gx[j + 0], gy[j + 0], gz[j + 0], RPTS + LPTS + j + 0);
            float c = PSTEP(gx[j + 1], gy[j + 1], gz[j + 1], RPTS + LPTS + j + 1);
            m2 = fmaxf(fmaxf(m2, a), c);
        }
        m2 = fmaxf(m2, PSTEP(gx[6], gy[6], gz[6], RPTS + LPTS + 6));

        // --- streamed batch B (slots 26..31), reuse temps ------------------
        #pragma unroll
        for (int j = 0; j < 6; ++j) {
            const int p = (RPTS + LPTS + 7 + j) * FT + t;
            gx[j] = xyz[3 * p + 0];
            gy[j] = xyz[3 * p + 1];
            gz[j] = xyz[3 * p + 2];
        }
        #pragma unroll
        for (int j = 0; j < 6; j += 2) {
            float a = PSTEP(gx[j + 0], gy[j + 0], gz[j + 0], RPTS + LPTS + 7 + j + 0);
            float c = PSTEP(gx[j + 1], gy[j + 1], gz[j + 1], RPTS + LPTS + 7 + j + 1);
            m3 = fmaxf(fmaxf(m3, a), c);
        }

        const float m = fmaxf(fmaxf(m0, m1), fmaxf(m2, m3));

        // --- wave max (butterfly -> all lanes) -----------------------------
        float wmax = m;
        #pragma unroll
        for (int mask = 32; mask >= 1; mask >>= 1)
            wmax = fmaxf(wmax, __shfl_xor(wmax, mask, 64));
        if ((t & 63) == 0) red[t >> 6] = wmax;
        __syncthreads();                              // A: red[] published

        // --- cross-wave max, computed redundantly by every wave ------------
        float g = red[t & 15];
        #pragma unroll
        for (int mask = 8; mask >= 1; mask >>= 1)
            g = fmaxf(g, __shfl_xor(g, mask, 64));

        if (t == 0) widx2[par ^ 1] = 0x7fffffff;      // reset for next iter

        // --- winner index: equality rescan + first-occurrence tie-break ----
        if (m == g) {
            int cand = 0x7fffffff;
            #pragma unroll
            for (int k = TPTS - 1; k >= 0; --k)
                if (D[k] == g) cand = k * FT + t;     // descending: lowest k wins
            atomicMin(&widx2[par], cand);
        }
        __syncthreads();                              // B: atomicMins done

        const int w = __builtin_amdgcn_readfirstlane(widx2[par]);
        const float* fw = xyz + 3 * w;                // uniform -> scalar loads
        fx = fw[0];
        fy = fw[1];
        fz = fw[2];
    }
#undef PSTEP

    if (t == 0)   // release the heaters
        __hip_atomic_store(flag, HEAT_DONE, __ATOMIC_RELAXED,
                           __HIP_MEMORY_SCOPE_AGENT);
}

// ---------------------------------------------------------------------------
// Kernel B: ball query — exact (d2, idx)-lexicographic 32-smallest per centroid
// ---------------------------------------------------------------------------
#define BT   256
#define BCAP 3072   // in-radius cap (expected worst ~1100 near origin)

__global__ __launch_bounds__(BT) void ballq_kernel(const float* __restrict__ xyz,
                                                   const float* __restrict__ newxyz,
                                                   int* __restrict__ gidx)
{
#pragma clang fp contract(off)
    __shared__ float Ld[BCAP + 128];
    __shared__ int   Li[BCAP + 128];
    __shared__ int   cnt, pcnt;
    __shared__ float cs[3];
    __shared__ float rv[BT / 64];
    __shared__ int   ri[BT / 64], rj[BT / 64];

    const int m = blockIdx.x;
    const int t = threadIdx.x;

    if (t == 0) {
        cnt = 0; pcnt = 0;
        cs[0] = newxyz[3 * m + 0];
        cs[1] = newxyz[3 * m + 1];
        cs[2] = newxyz[3 * m + 2];
    }
    __syncthreads();
    const float cx = cs[0], cy = cs[1], cz = cs[2];

    for (int p = t; p < NPTS; p += BT) {
        float dx = cx - xyz[3 * p + 0];
        float dy = cy - xyz[3 * p + 1];
        float dz = cz - xyz[3 * p + 2];
        float d2 = ((dx * dx) + (dy * dy)) + (dz * dz);
        if (!(d2 > RADIUS2)) {                    // in radius (keeps d2 == r^2)
            int pos = atomicAdd(&cnt, 1);
            if (pos < BCAP) { Ld[pos] = d2; Li[pos] = p; }
        } else if (p < 128) {                     // padding candidates (masked 1e9)
            int pos = atomicAdd(&pcnt, 1);
            Ld[BCAP + pos] = 1e9f;
            Li[BCAP + pos] = p;
        }
    }
    __syncthreads();

    const int L = (cnt < BCAP) ? cnt : BCAP;
    const int P = pcnt;
    if (t < P) {  // compact pads to follow the in-radius list
        float d = Ld[BCAP + t];
        int   x = Li[BCAP + t];
        Ld[L + t] = d;
        Li[L + t] = x;
    }
    __syncthreads();
    const int M = L + P;

    for (int r = 0; r < NSAMPLE; ++r) {
        float bd = 3e38f;
        int   bi = 0x7fffffff;
        int   bj = 0;
        for (int j = t; j < M; j += BT) {
            float d = Ld[j];
            int   x = Li[j];
            if (d < bd || (d == bd && x < bi)) { bd = d; bi = x; bj = j; }
        }
        #pragma unroll
        for (int mask = 32; mask >= 1; mask >>= 1) {
            float ov = __shfl_xor(bd, mask, 64);
            int   oi = __shfl_xor(bi, mask, 64);
            int   oj = __shfl_xor(bj, mask, 64);
            if (ov < bd || (ov == bd && oi < bi)) { bd = ov; bi = oi; bj = oj; }
        }
        if ((t & 63) == 0) { rv[t >> 6] = bd; ri[t >> 6] = bi; rj[t >> 6] = bj; }
        __syncthreads();
        if (t == 0) {
            float v0 = rv[0]; int i0 = ri[0]; int j0 = rj[0];
            for (int w = 1; w < BT / 64; ++w) {
                if (rv[w] < v0 || (rv[w] == v0 && ri[w] < i0)) { v0 = rv[w]; i0 = ri[w]; j0 = rj[w]; }
            }
            gidx[m * NSAMPLE + r] = i0;
            Ld[j0] = 3e38f;   // remove from candidate set
        }
        __syncthreads();
    }
}

// ---------------------------------------------------------------------------
// Kernel C: gather -> MLP(67->64->128, exact GELU) -> maxpool, 1 block/centroid
// ---------------------------------------------------------------------------
__global__ __launch_bounds__(256) void mlp_kernel(const float* __restrict__ xyz,
                                                  const float* __restrict__ feat,
                                                  const float* __restrict__ W1,
                                                  const float* __restrict__ b1,
                                                  const float* __restrict__ W2,
                                                  const float* __restrict__ b2,
                                                  const float* __restrict__ newxyz,
                                                  const int* __restrict__ gidx,
                                                  float* __restrict__ out_pooled)
{
    __shared__ float W1s[D0 * H1DIM];            // 17152 B
    __shared__ float W2s[H1DIM * H2DIM];         // 32768 B
    __shared__ float b1s[H1DIM];
    __shared__ float b2s[H2DIM];
    __shared__ float Xs[NSAMPLE][D0 + 1];        // 68 stride
    __shared__ float H1s[NSAMPLE][H1DIM + 4];    // 68 stride
    __shared__ float H2s[NSAMPLE][H2DIM + 4];    // 132 stride
    __shared__ int   idxs[NSAMPLE];
    __shared__ float cs[3];

    const int m = blockIdx.x;
    const int t = threadIdx.x;

    for (int i = t; i < D0 * H1DIM; i += 256) W1s[i] = W1[i];
    for (int i = t; i < H1DIM * H2DIM; i += 256) W2s[i] = W2[i];
    if (t < H1DIM) b1s[t] = b1[t];
    if (t < H2DIM) b2s[t] = b2[t];
    if (t < NSAMPLE) idxs[t] = gidx[m * NSAMPLE + t];
    if (t < 3) cs[t] = newxyz[3 * m + t];
    __syncthreads();

    const int s  = t >> 3;   // sample 0..31
    const int u  = t & 7;    // sub-worker 0..7

    {   // gather: g_xyz (relative) + feat
        const int id = idxs[s];
        const float4* f4 = (const float4*)(feat + (size_t)id * D_IN);
        float4 a = f4[u * 2 + 0];
        float4 b = f4[u * 2 + 1];
        Xs[s][3 + u * 8 + 0] = a.x; Xs[s][3 + u * 8 + 1] = a.y;
        Xs[s][3 + u * 8 + 2] = a.z; Xs[s][3 + u * 8 + 3] = a.w;
        Xs[s][3 + u * 8 + 4] = b.x; Xs[s][3 + u * 8 + 5] = b.y;
        Xs[s][3 + u * 8 + 6] = b.z; Xs[s][3 + u * 8 + 7] = b.w;
        if (u == 0) {
            Xs[s][0] = xyz[3 * id + 0] - cs[0];
            Xs[s][1] = xyz[3 * id + 1] - cs[1];
            Xs[s][2] = xyz[3 * id + 2] - cs[2];
        }
    }
    __syncthreads();

    // layer 1: each thread computes 8 of 64 outputs for its sample
    {
        float acc[8];
        #pragma unroll
        for (int v = 0; v < 8; ++v) acc[v] = b1s[u * 8 + v];
        for (int k = 0; k < D0; ++k) {
            float xk = Xs[s][k];
            float4 wa = *(const float4*)&W1s[k * H1DIM + u * 8 + 0];
            float4 wb = *(const float4*)&W1s[k * H1DIM + u * 8 + 4];
            acc[0] = fmaf(xk, wa.x, acc[0]); acc[1] = fmaf(xk, wa.y, acc[1]);
            acc[2] = fmaf(xk, wa.z, acc[2]); acc[3] = fmaf(xk, wa.w, acc[3]);
            acc[4] = fmaf(xk, wb.x, acc[4]); acc[5] = fmaf(xk, wb.y, acc[5]);
            acc[6] = fmaf(xk, wb.z, acc[6]); acc[7] = fmaf(xk, wb.w, acc[7]);
        }
        #pragma unroll
        for (int v = 0; v < 8; ++v) {
            float a = acc[v];
            H1s[s][u * 8 + v] = 0.5f * a * (1.0f + erff(a * 0.70710678118654752f));
        }
    }
    __syncthreads();

    // layer 2: each thread computes 16 of 128 outputs for its sample
    {
        float acc[16];
        #pragma unroll
        for (int v = 0; v < 16; ++v) acc[v] = b2s[u * 16 + v];
        for (int k = 0; k < H1DIM; ++k) {
            float hk = H1s[s][k];
            #pragma unroll
            for (int q = 0; q < 4; ++q) {
                float4 w = *(const float4*)&W2s[k * H2DIM + u * 16 + q * 4];
                acc[q * 4 + 0] = fmaf(hk, w.x, acc[q * 4 + 0]);
                acc[q * 4 + 1] = fmaf(hk, w.y, acc[q * 4 + 1]);
                acc[q * 4 + 2] = fmaf(hk, w.z, acc[q * 4 + 2]);
                acc[q * 4 + 3] = fmaf(hk, w.w, acc[q * 4 + 3]);
            }
        }
        #pragma unroll
        for (int v = 0; v < 16; ++v) {
            float a = acc[v];
            H2s[s][u * 16 + v] = 0.5f * a * (1.0f + erff(a * 0.70710678118654752f));
        }
    }
    __syncthreads();

    // maxpool over 32 samples
    if (t < H2DIM) {
        float mx = H2s[0][t];
        #pragma unroll 4
        for (int ss = 1; ss < NSAMPLE; ++ss) mx = fmaxf(mx, H2s[ss][t]);
        out_pooled[(size_t)m * H2DIM + t] = mx;
    }
}

// ---------------------------------------------------------------------------
extern "C" void kernel_launch(void* const* d_in, const int* in_sizes, int n_in,
                              void* d_out, int out_size, void* d_ws, size_t ws_size,
                              hipStream_t stream) {
    const float* xyz  = (const float*)d_in[0];
    const float* feat = (const float*)d_in[1];
    const float* W1   = (const float*)d_in[2];
    const float* b1   = (const float*)d_in[3];
    const float* W2   = (const float*)d_in[4];
    const float* b2   = (const float*)d_in[5];
    float* out = (float*)d_out;
    int*   gidx = (int*)d_ws;                               // 256 KiB
    unsigned int* flag = (unsigned int*)((char*)d_ws + NPOINT * NSAMPLE * 4);
    // ws poison 0xAAAAAAAA != HEAT_DONE -> heater armed each call.

    // heater guard dump lands in the pooled-output region (never written;
    // mlp overwrites it anyway)
    float* hdump = out + 3 * NPOINT + 4096;

    fps_heat_kernel<<<256, 1024, 0, stream>>>(xyz, out, flag, hdump);
    ballq_kernel<<<NPOINT, BT, 0, stream>>>(xyz, out, gidx);
    mlp_kernel<<<NPOINT, 256, 0, stream>>>(xyz, feat, W1, b1, W2, b2,
                                           out, gidx, out + 3 * NPOINT);
}

// Round 3
// 6108.931 us; speedup vs baseline: 1.0147x; 1.0147x over previous
//
#include <hip/hip_runtime.h>
#include <math.h>

#define NPTS    32768
#define NPOINT  2048
#define NSAMPLE 32
#define RADIUS2 0.25f
#define D_IN    64
#define D0      67
#define H1DIM   64
#define H2DIM   128

// ---------------------------------------------------------------------------
// Kernel A: SINGLE-BLOCK FPS + heaters.
// R11: single 1024-thread block does the full 32K-point distance update +
// argmax on ONE CU -- no fabric on the critical path (the 32-block version
// was stuck at 2.17us/iter of cross-XCD publish->observe latency).
// R12: launch_bounds(1024,4) didn't move VGPR_Count or time -> spills were
// never the binding constraint.
// R13 theory: two residual costs. (a) FPS LDS was 62KB, so a 1024-thread
// HEATER block co-resided on the FPS CU (2x62KB fits) and its never-stalling
// FMA waves stole VALU issue from the 16 FPS waves all dispatch long.
// (b) 13 L2-streamed points/thread = 160KB/iter through one CU's L1-miss
// path (~32B/cy) ~= 5000cy > the 2720cy VALU floor.
// Fix: dynamic LDS = 156KB (opt-in; gfx950 supports 160KB/WG -- AITER fmha
// uses it). LPTS 5->13 (planar float2+float, conflict-free), GPTS 13->5
// (stream 160KB->61KB/iter, hidden under VALU), and the 160KB footprint
// forcibly evicts heaters from the FPS CU (1 block/CU everywhere).
// Argmax: wave butterfly -> 16-entry LDS -> redundant cross-wave butterfly
// -> equality rescan + LDS atomicMin (exact first-occurrence tie-break ==
// jnp.argmax). widx ping-pong parity slots remove the 3rd barrier.
// Exact numerics: op order sub,mul,mul,add,mul,add,fminf under contract(off).
// Heaters: blocks 1..255, 256 active threads each keep clocks up for the
// tail kernels (measured: tail 350us -> 30us with heat).
// ---------------------------------------------------------------------------
#define FT    1024
#define RPTS  14                 // register-resident points / thread
#define LPTS  13                 // LDS-resident points / thread (156KB)
#define GPTS  5                  // L2-streamed points / thread
#define TPTS  (RPTS + LPTS + GPTS)   // 32; TPTS*FT == NPTS
#define HEAT_DONE 0x600DD00Du
#define HEAT_CAP  4096           // outer-loop safety cap (~55ms)

#define SMEM_BYTES (LPTS * FT * 12 + 64 + 8)   // LXY + LZ + red[16] + widx2[2]

__global__ __launch_bounds__(1024, 4) void fps_heat_kernel(const float* __restrict__ xyz,
                                                           float* __restrict__ d_out,
                                                           unsigned int* __restrict__ flag,
                                                           float* __restrict__ hdump)
{
#pragma clang fp contract(off)
    const int t = threadIdx.x;
    const int b = blockIdx.x;

    if (b != 0) {
        // ----------------- HEATER: dense FMA, poll flag every ~13us --------
        if (t >= 256) return;    // 4 active waves/heater block
        float a0 = 1.0f + (float)(b * 256 + t) * 1e-6f;
        float a1 = a0 + 0.1f, a2 = a0 + 0.2f, a3 = a0 + 0.3f;
        float a4 = a0 + 0.4f, a5 = a0 + 0.5f, a6 = a0 + 0.6f, a7 = a0 + 0.7f;
        for (int outer = 0; outer < HEAT_CAP; ++outer) {
            #pragma unroll 8
            for (int n = 0; n < 2048; ++n) {
                a0 = fmaf(a0, 0.9999999f, 1e-7f);
                a1 = fmaf(a1, 0.9999999f, 1e-7f);
                a2 = fmaf(a2, 0.9999999f, 1e-7f);
                a3 = fmaf(a3, 0.9999999f, 1e-7f);
                a4 = fmaf(a4, 0.9999999f, 1e-7f);
                a5 = fmaf(a5, 0.9999999f, 1e-7f);
                a6 = fmaf(a6, 0.9999999f, 1e-7f);
                a7 = fmaf(a7, 0.9999999f, 1e-7f);
            }
            if (__hip_atomic_load(flag, __ATOMIC_RELAXED,
                                  __HIP_MEMORY_SCOPE_AGENT) == HEAT_DONE)
                break;
        }
        float s = a0 + a1 + a2 + a3 + a4 + a5 + a6 + a7;
        if (s == 1234.56789f) hdump[(b - 1) * 256 + t] = s;   // never true
        return;
    }

    // ------------------------------ FPS block ------------------------------
    extern __shared__ unsigned char smem_raw[];
    float2* LXY   = (float2*)smem_raw;                               // 104 KB
    float*  LZ    = (float*)(smem_raw + (size_t)LPTS * FT * 8);      //  52 KB
    float*  red   = (float*)(smem_raw + (size_t)LPTS * FT * 12);     //  64 B
    int*    widx2 = (int*)  (smem_raw + (size_t)LPTS * FT * 12 + 64);

    float X[RPTS], Y[RPTS], Z[RPTS];
    float D[TPTS];
    #pragma unroll
    for (int k = 0; k < TPTS; ++k) D[k] = 1e38f;

    // one-time staging: slots 0..13 -> regs, 14..26 -> LDS
    #pragma unroll
    for (int k = 0; k < RPTS; ++k) {
        const int p = k * FT + t;
        X[k] = xyz[3 * p + 0];
        Y[k] = xyz[3 * p + 1];
        Z[k] = xyz[3 * p + 2];
    }
    #pragma unroll
    for (int j = 0; j < LPTS; ++j) {
        const int p = (RPTS + j) * FT + t;
        LXY[j * FT + t] = make_float2(xyz[3 * p + 0], xyz[3 * p + 1]);
        LZ [j * FT + t] = xyz[3 * p + 2];
    }
    if (t == 0) { widx2[0] = 0x7fffffff; widx2[1] = 0x7fffffff; }
    float fx = xyz[0], fy = xyz[1], fz = xyz[2];   // far = 0 at start
    __syncthreads();

// one point: exact op order (sub, mul, mul, add, mul, add, fmin)
#define PSTEP(px, py, pz, slot) ({                          \
        float dx_ = (px) - fx, dy_ = (py) - fy, dz_ = (pz) - fz; \
        float d_  = ((dx_ * dx_) + (dy_ * dy_)) + (dz_ * dz_);   \
        float Dn_ = fminf(D[slot], d_);                          \
        D[slot] = Dn_;                                           \
        Dn_; })

    for (int i = 0; i < NPOINT; ++i) {
        const int par = i & 1;

        if (t == 0) {   // emit current far point's coords
            d_out[3 * i + 0] = fx;
            d_out[3 * i + 1] = fy;
            d_out[3 * i + 2] = fz;
        }

        float m0 = -1.0f, m1 = -1.0f, m2 = -1.0f;

        // --- L2-streamed loads issued early (slots 27..31) -----------------
        float gx[GPTS], gy[GPTS], gz[GPTS];
        #pragma unroll
        for (int j = 0; j < GPTS; ++j) {
            const int p = (RPTS + LPTS + j) * FT + t;
            gx[j] = xyz[3 * p + 0];
            gy[j] = xyz[3 * p + 1];
            gz[j] = xyz[3 * p + 2];
        }

        // --- register slice (slots 0..13) ----------------------------------
        #pragma unroll
        for (int k = 0; k < RPTS; k += 2) {
            float a = PSTEP(X[k + 0], Y[k + 0], Z[k + 0], k + 0);
            float c = PSTEP(X[k + 1], Y[k + 1], Z[k + 1], k + 1);
            m0 = fmaxf(fmaxf(m0, a), c);
        }

        // --- LDS slice (slots 14..26) --------------------------------------
        #pragma unroll
        for (int j = 0; j < LPTS - 1; j += 2) {
            float2 q0 = LXY[(j + 0) * FT + t]; float z0 = LZ[(j + 0) * FT + t];
            float2 q1 = LXY[(j + 1) * FT + t]; float z1 = LZ[(j + 1) * FT + t];
            float a = PSTEP(q0.x, q0.y, z0, RPTS + j + 0);
            float c = PSTEP(q1.x, q1.y, z1, RPTS + j + 1);
            m1 = fmaxf(fmaxf(m1, a), c);
        }
        {
            const int j = LPTS - 1;
            float2 q = LXY[j * FT + t]; float z = LZ[j * FT + t];
            m1 = fmaxf(m1, PSTEP(q.x, q.y, z, RPTS + j));
        }

        // --- streamed compute (slots 27..31) -------------------------------
        #pragma unroll
        for (int j = 0; j < GPTS - 1; j += 2) {
            float a = PSTEP(gx[j + 0], gy[j + 0], gz[j + 0], RPTS + LPTS + j + 0);
            float c = PSTEP(gx[j + 1], gy[j + 1], gz[j + 1], RPTS + LPTS + j + 1);
            m2 = fmaxf(fmaxf(m2, a), c);
        }
        m2 = fmaxf(m2, PSTEP(gx[GPTS - 1], gy[GPTS - 1], gz[GPTS - 1],
                             RPTS + LPTS + GPTS - 1));

        const float m = fmaxf(fmaxf(m0, m1), m2);

        // --- wave max (butterfly -> all lanes) -----------------------------
        float wmax = m;
        #pragma unroll
        for (int mask = 32; mask >= 1; mask >>= 1)
            wmax = fmaxf(wmax, __shfl_xor(wmax, mask, 64));
        if ((t & 63) == 0) red[t >> 6] = wmax;
        __syncthreads();                              // A: red[] published

        // --- cross-wave max, computed redundantly by every wave ------------
        float g = red[t & 15];
        #pragma unroll
        for (int mask = 8; mask >= 1; mask >>= 1)
            g = fmaxf(g, __shfl_xor(g, mask, 64));

        if (t == 0) widx2[par ^ 1] = 0x7fffffff;      // reset for next iter

        // --- winner index: equality rescan + first-occurrence tie-break ----
        if (m == g) {
            int cand = 0x7fffffff;
            #pragma unroll
            for (int k = TPTS - 1; k >= 0; --k)
                if (D[k] == g) cand = k * FT + t;     // descending: lowest k wins
            atomicMin(&widx2[par], cand);
        }
        __syncthreads();                              // B: atomicMins done

        const int w = __builtin_amdgcn_readfirstlane(widx2[par]);
        const float* fw = xyz + 3 * w;                // uniform -> scalar loads
        fx = fw[0];
        fy = fw[1];
        fz = fw[2];
    }
#undef PSTEP

    if (t == 0)   // release the heaters
        __hip_atomic_store(flag, HEAT_DONE, __ATOMIC_RELAXED,
                           __HIP_MEMORY_SCOPE_AGENT);
}

// ---------------------------------------------------------------------------
// Kernel B: ball query — exact (d2, idx)-lexicographic 32-smallest per centroid
// ---------------------------------------------------------------------------
#define BT   256
#define BCAP 3072   // in-radius cap (expected worst ~1100 near origin)

__global__ __launch_bounds__(BT) void ballq_kernel(const float* __restrict__ xyz,
                                                   const float* __restrict__ newxyz,
                                                   int* __restrict__ gidx)
{
#pragma clang fp contract(off)
    __shared__ float Ld[BCAP + 128];
    __shared__ int   Li[BCAP + 128];
    __shared__ int   cnt, pcnt;
    __shared__ float cs[3];
    __shared__ float rv[BT / 64];
    __shared__ int   ri[BT / 64], rj[BT / 64];

    const int m = blockIdx.x;
    const int t = threadIdx.x;

    if (t == 0) {
        cnt = 0; pcnt = 0;
        cs[0] = newxyz[3 * m + 0];
        cs[1] = newxyz[3 * m + 1];
        cs[2] = newxyz[3 * m + 2];
    }
    __syncthreads();
    const float cx = cs[0], cy = cs[1], cz = cs[2];

    for (int p = t; p < NPTS; p += BT) {
        float dx = cx - xyz[3 * p + 0];
        float dy = cy - xyz[3 * p + 1];
        float dz = cz - xyz[3 * p + 2];
        float d2 = ((dx * dx) + (dy * dy)) + (dz * dz);
        if (!(d2 > RADIUS2)) {                    // in radius (keeps d2 == r^2)
            int pos = atomicAdd(&cnt, 1);
            if (pos < BCAP) { Ld[pos] = d2; Li[pos] = p; }
        } else if (p < 128) {                     // padding candidates (masked 1e9)
            int pos = atomicAdd(&pcnt, 1);
            Ld[BCAP + pos] = 1e9f;
            Li[BCAP + pos] = p;
        }
    }
    __syncthreads();

    const int L = (cnt < BCAP) ? cnt : BCAP;
    const int P = pcnt;
    if (t < P) {  // compact pads to follow the in-radius list
        float d = Ld[BCAP + t];
        int   x = Li[BCAP + t];
        Ld[L + t] = d;
        Li[L + t] = x;
    }
    __syncthreads();
    const int M = L + P;

    for (int r = 0; r < NSAMPLE; ++r) {
        float bd = 3e38f;
        int   bi = 0x7fffffff;
        int   bj = 0;
        for (int j = t; j < M; j += BT) {
            float d = Ld[j];
            int   x = Li[j];
            if (d < bd || (d == bd && x < bi)) { bd = d; bi = x; bj = j; }
        }
        #pragma unroll
        for (int mask = 32; mask >= 1; mask >>= 1) {
            float ov = __shfl_xor(bd, mask, 64);
            int   oi = __shfl_xor(bi, mask, 64);
            int   oj = __shfl_xor(bj, mask, 64);
            if (ov < bd || (ov == bd && oi < bi)) { bd = ov; bi = oi; bj = oj; }
        }
        if ((t & 63) == 0) { rv[t >> 6] = bd; ri[t >> 6] = bi; rj[t >> 6] = bj; }
        __syncthreads();
        if (t == 0) {
            float v0 = rv[0]; int i0 = ri[0]; int j0 = rj[0];
            for (int w = 1; w < BT / 64; ++w) {
                if (rv[w] < v0 || (rv[w] == v0 && ri[w] < i0)) { v0 = rv[w]; i0 = ri[w]; j0 = rj[w]; }
            }
            gidx[m * NSAMPLE + r] = i0;
            Ld[j0] = 3e38f;   // remove from candidate set
        }
        __syncthreads();
    }
}

// ---------------------------------------------------------------------------
// Kernel C: gather -> MLP(67->64->128, exact GELU) -> maxpool, 1 block/centroid
// ---------------------------------------------------------------------------
__global__ __launch_bounds__(256) void mlp_kernel(const float* __restrict__ xyz,
                                                  const float* __restrict__ feat,
                                                  const float* __restrict__ W1,
                                                  const float* __restrict__ b1,
                                                  const float* __restrict__ W2,
                                                  const float* __restrict__ b2,
                                                  const float* __restrict__ newxyz,
                                                  const int* __restrict__ gidx,
                                                  float* __restrict__ out_pooled)
{
    __shared__ float W1s[D0 * H1DIM];            // 17152 B
    __shared__ float W2s[H1DIM * H2DIM];         // 32768 B
    __shared__ float b1s[H1DIM];
    __shared__ float b2s[H2DIM];
    __shared__ float Xs[NSAMPLE][D0 + 1];        // 68 stride
    __shared__ float H1s[NSAMPLE][H1DIM + 4];    // 68 stride
    __shared__ float H2s[NSAMPLE][H2DIM + 4];    // 132 stride
    __shared__ int   idxs[NSAMPLE];
    __shared__ float cs[3];

    const int m = blockIdx.x;
    const int t = threadIdx.x;

    for (int i = t; i < D0 * H1DIM; i += 256) W1s[i] = W1[i];
    for (int i = t; i < H1DIM * H2DIM; i += 256) W2s[i] = W2[i];
    if (t < H1DIM) b1s[t] = b1[t];
    if (t < H2DIM) b2s[t] = b2[t];
    if (t < NSAMPLE) idxs[t] = gidx[m * NSAMPLE + t];
    if (t < 3) cs[t] = newxyz[3 * m + t];
    __syncthreads();

    const int s  = t >> 3;   // sample 0..31
    const int u  = t & 7;    // sub-worker 0..7

    {   // gather: g_xyz (relative) + feat
        const int id = idxs[s];
        const float4* f4 = (const float4*)(feat + (size_t)id * D_IN);
        float4 a = f4[u * 2 + 0];
        float4 b = f4[u * 2 + 1];
        Xs[s][3 + u * 8 + 0] = a.x; Xs[s][3 + u * 8 + 1] = a.y;
        Xs[s][3 + u * 8 + 2] = a.z; Xs[s][3 + u * 8 + 3] = a.w;
        Xs[s][3 + u * 8 + 4] = b.x; Xs[s][3 + u * 8 + 5] = b.y;
        Xs[s][3 + u * 8 + 6] = b.z; Xs[s][3 + u * 8 + 7] = b.w;
        if (u == 0) {
            Xs[s][0] = xyz[3 * id + 0] - cs[0];
            Xs[s][1] = xyz[3 * id + 1] - cs[1];
            Xs[s][2] = xyz[3 * id + 2] - cs[2];
        }
    }
    __syncthreads();

    // layer 1: each thread computes 8 of 64 outputs for its sample
    {
        float acc[8];
        #pragma unroll
        for (int v = 0; v < 8; ++v) acc[v] = b1s[u * 8 + v];
        for (int k = 0; k < D0; ++k) {
            float xk = Xs[s][k];
            float4 wa = *(const float4*)&W1s[k * H1DIM + u * 8 + 0];
            float4 wb = *(const float4*)&W1s[k * H1DIM + u * 8 + 4];
            acc[0] = fmaf(xk, wa.x, acc[0]); acc[1] = fmaf(xk, wa.y, acc[1]);
            acc[2] = fmaf(xk, wa.z, acc[2]); acc[3] = fmaf(xk, wa.w, acc[3]);
            acc[4] = fmaf(xk, wb.x, acc[4]); acc[5] = fmaf(xk, wb.y, acc[5]);
            acc[6] = fmaf(xk, wb.z, acc[6]); acc[7] = fmaf(xk, wb.w, acc[7]);
        }
        #pragma unroll
        for (int v = 0; v < 8; ++v) {
            float a = acc[v];
            H1s[s][u * 8 + v] = 0.5f * a * (1.0f + erff(a * 0.70710678118654752f));
        }
    }
    __syncthreads();

    // layer 2: each thread computes 16 of 128 outputs for its sample
    {
        float acc[16];
        #pragma unroll
        for (int v = 0; v < 16; ++v) acc[v] = b2s[u * 16 + v];
        for (int k = 0; k < H1DIM; ++k) {
            float hk = H1s[s][k];
            #pragma unroll
            for (int q = 0; q < 4; ++q) {
                float4 w = *(const float4*)&W2s[k * H2DIM + u * 16 + q * 4];
                acc[q * 4 + 0] = fmaf(hk, w.x, acc[q * 4 + 0]);
                acc[q * 4 + 1] = fmaf(hk, w.y, acc[q * 4 + 1]);
                acc[q * 4 + 2] = fmaf(hk, w.z, acc[q * 4 + 2]);
                acc[q * 4 + 3] = fmaf(hk, w.w, acc[q * 4 + 3]);
            }
        }
        #pragma unroll
        for (int v = 0; v < 16; ++v) {
            float a = acc[v];
            H2s[s][u * 16 + v] = 0.5f * a * (1.0f + erff(a * 0.70710678118654752f));
        }
    }
    __syncthreads();

    // maxpool over 32 samples
    if (t < H2DIM) {
        float mx = H2s[0][t];
        #pragma unroll 4
        for (int ss = 1; ss < NSAMPLE; ++ss) mx = fmaxf(mx, H2s[ss][t]);
        out_pooled[(size_t)m * H2DIM + t] = mx;
    }
}

// ---------------------------------------------------------------------------
extern "C" void kernel_launch(void* const* d_in, const int* in_sizes, int n_in,
                              void* d_out, int out_size, void* d_ws, size_t ws_size,
                              hipStream_t stream) {
    const float* xyz  = (const float*)d_in[0];
    const float* feat = (const float*)d_in[1];
    const float* W1   = (const float*)d_in[2];
    const float* b1   = (const float*)d_in[3];
    const float* W2   = (const float*)d_in[4];
    const float* b2   = (const float*)d_in[5];
    float* out = (float*)d_out;
    int*   gidx = (int*)d_ws;                               // 256 KiB
    unsigned int* flag = (unsigned int*)((char*)d_ws + NPOINT * NSAMPLE * 4);
    // ws poison 0xAAAAAAAA != HEAT_DONE -> heater armed each call.

    // heater guard dump lands in the pooled-output region (never written;
    // mlp overwrites it anyway)
    float* hdump = out + 3 * NPOINT + 4096;

    // opt-in to >64KB dynamic LDS (gfx950 supports 160KB/WG)
    (void)hipFuncSetAttribute((const void*)fps_heat_kernel,
                              hipFuncAttributeMaxDynamicSharedMemorySize,
                              SMEM_BYTES);

    fps_heat_kernel<<<256, 1024, SMEM_BYTES, stream>>>(xyz, out, flag, hdump);
    ballq_kernel<<<NPOINT, BT, 0, stream>>>(xyz, out, gidx);
    mlp_kernel<<<NPOINT, 256, 0, stream>>>(xyz, feat, W1, b1, W2, b2,
                                           out, gidx, out + 3 * NPOINT);
}